// Round 8
// baseline (188.287 us; speedup 1.0000x reference)
//
#include <hip/hip_runtime.h>
#include <hip/hip_bf16.h>
#include <math.h>

// Problem constants (fixed by the reference setup_inputs()).
#define B_SZ    16384
#define NNZ     32
#define FT_OUT  1024
#define FEAT    768
#define BUCKETS 8
#define M_TOT   (2 * B_SZ)        // stm rows then nstm rows

typedef __bf16 bf16x8 __attribute__((ext_vector_type(8)));
typedef float  f32x4  __attribute__((ext_vector_type(4)));
typedef __attribute__((ext_vector_type(8))) short short8;

__device__ __forceinline__ unsigned short f2b(float f) {
    return __bfloat16_as_ushort(__float2bfloat16(f));
}
__device__ __forceinline__ float b2f(unsigned short u) {
    union { unsigned int i; float f; } x; x.i = ((unsigned int)u) << 16; return x.f;
}
__device__ __forceinline__ void gld_lds16(const void* g, void* l) {
    __builtin_amdgcn_global_load_lds(
        (const __attribute__((address_space(1))) unsigned int*)g,
        (__attribute__((address_space(3))) unsigned int*)l, 16, 0, 0);
}

// ---------------------------------------------------------------------------
// Kernel P (fused prep): blocks 0..8191 scatter boards -> dense bf16 A;
// blocks 8192..8203 cast ft_w fp32->bf16; blocks 8204..8219 zero logit.
// Fusing removes 2 dispatch gaps (R6/R7 showed ~83us of non-gemm wall time).
// ---------------------------------------------------------------------------
#define PREP_BUILD  8192
#define PREP_CVT    12
#define PREP_ZERO   16

__global__ __launch_bounds__(256) void prep(
    const int*    __restrict__ stm_idx, const int* __restrict__ nstm_idx,
    const float*  __restrict__ values,
    const float2* __restrict__ ftw2,    unsigned int* __restrict__ Wout,
    unsigned short* __restrict__ A,     float* __restrict__ logit) {
    const int bid = blockIdx.x;
    if (bid < PREP_BUILD) {
        __shared__ float rowbuf[4][FEAT];
        const int wave = threadIdx.x >> 6, lane = threadIdx.x & 63;
        const int m = bid * 4 + wave;
        const int board = m & (B_SZ - 1);
        const int* idx = (m >= B_SZ) ? nstm_idx : stm_idx;
        float* rb = rowbuf[wave];
#pragma unroll
        for (int i = 0; i < FEAT / 64; ++i) rb[i * 64 + lane] = 0.0f;
        __syncthreads();
        if (lane < NNZ) {
            int   f = idx[(board * NNZ + lane) * 2 + 1];
            float v = values[board * NNZ + lane];
            atomicAdd(&rb[f], v);   // duplicate (b,f) must SUM (coo.to_dense)
        }
        __syncthreads();
        unsigned int* dst = (unsigned int*)(A + (long)m * FEAT);
#pragma unroll
        for (int i = 0; i < FEAT / 128; ++i) {
            int e = i * 64 + lane;
            unsigned int lo = f2b(rb[2 * e]), hi = f2b(rb[2 * e + 1]);
            dst[e] = lo | (hi << 16);
        }
    } else if (bid < PREP_BUILD + PREP_CVT) {
        int tid = (bid - PREP_BUILD) * 256 + threadIdx.x;
        for (int i = tid; i < FT_OUT * FEAT / 2; i += PREP_CVT * 256) {
            float2 v = ftw2[i];
            Wout[i] = (unsigned int)f2b(v.x) | ((unsigned int)f2b(v.y) << 16);
        }
    } else {
        int tid = (bid - PREP_BUILD - PREP_CVT) * 256 + threadIdx.x;
        for (int i = tid; i < B_SZ; i += PREP_ZERO * 256) logit[i] = 0.0f;
    }
}

// ---------------------------------------------------------------------------
// Kernel C: 256x256 bf16 MFMA GEMM, counted-vmcnt schedule (T3/T4 mechanics):
// per K-step:  STAGE(t+1 -> buf^1)        ; loads stay IN FLIGHT
//              s_waitcnt vmcnt(8)          ; tile t landed (never 0 mid-loop)
//              s_barrier (raw)             ; all waves' tile-t loads landed
//              ds_read frags + 64 MFMA (setprio wrap, T5)
//              s_barrier (raw)             ; buf^1 free for next restage
// Race-free by construction: stage of buf^1 only after the barrier that ends
// the iteration which read buf^1; reads of buf b only after vmcnt+barrier.
// T2 both-sides XOR swizzle kept (R7: bank conflicts = 0). T1 XCD swizzle
// kept (512 wg % 8 == 0 -> simple form bijective), N fastest.
// ---------------------------------------------------------------------------
#define BM 256
#define BN 256
#define BK 64
#define NKT (FEAT / BK)           // 12 K-steps

__global__ __launch_bounds__(512, 1) void gemm_head(
    const unsigned short* __restrict__ A,   // [M_TOT][FEAT] bf16
    const unsigned short* __restrict__ W,   // [FT_OUT][FEAT] bf16
    const float* __restrict__ ft_b,         // [FT_OUT]
    const float* __restrict__ out_w,        // [BUCKETS][2*FT_OUT]
    const int*   __restrict__ buckets,      // [B_SZ]
    float*       __restrict__ logit)        // [B_SZ], pre-zeroed
{
    __shared__ unsigned short smA[2][BM * BK];   // 2 x 32 KB
    __shared__ unsigned short smB[2][BN * BK];   // 2 x 32 KB   (128 KB total)
    const int wv = threadIdx.x >> 6, lane = threadIdx.x & 63;
    const int wm = wv >> 2, wn = wv & 3;             // 2x4 wave grid

    // T1: 512 wgs, xcd = bid&7 owns 64 contiguous ids; n fastest (4 N-tiles).
    const int bid = blockIdx.x;
    const int wg  = (bid & 7) * 64 + (bid >> 3);
    const int tileM = (wg >> 2) * BM;                // 128 M-tiles
    const int tileN = (wg & 3) * BN;                 // 4 N-tiles

    f32x4 acc[8][4] = {};

    const int srow  = wv * 32 + (lane >> 3);         // staging row (q adds 8)
    const int skoff = ((lane & 7) ^ (lane >> 3)) * 8;  // T2 source pre-swizzle

    // per-thread per tile: 4 loads A + 4 loads W = 8  -> vmcnt counts by 8
#define STAGE(buf, kt)                                                        \
    {                                                                         \
        const int k0_ = (kt) * BK;                                            \
        _Pragma("unroll")                                                     \
        for (int q = 0; q < 4; ++q) {                                         \
            gld_lds16(A + (long)(tileM + srow + q * 8) * FEAT + k0_ + skoff,  \
                      &smA[buf][(wv * 32 + q * 8) * BK]);                     \
            gld_lds16(W + (long)(tileN + srow + q * 8) * FEAT + k0_ + skoff,  \
                      &smB[buf][(wv * 32 + q * 8) * BK]);                     \
        }                                                                     \
    }

    const int cx = lane & 7;                         // read-side xor key
    const int rq = lane >> 4;                        // k-quarter 0..3

    STAGE(0, 0);                                     // 8 loads in flight

    for (int t = 0; t < NKT; ++t) {
        const int b = t & 1;
        if (t + 1 < NKT) {
            STAGE(b ^ 1, t + 1);                     // 16 in flight
            asm volatile("s_waitcnt vmcnt(8)" ::: "memory");   // tile t landed
        } else {
            asm volatile("s_waitcnt vmcnt(0)" ::: "memory");   // last tile
        }
        __builtin_amdgcn_s_barrier();                // raw: no vmcnt(0) drain
        asm volatile("" ::: "memory");
#pragma unroll
        for (int ki = 0; ki < 2; ++ki) {
            const int koff = ((ki * 4 + rq) ^ cx) * 8;   // swizzled chunk
            bf16x8 af[8], bfr[4];
#pragma unroll
            for (int f = 0; f < 8; ++f)
                af[f] = *(const bf16x8*)(&smA[b][(wm * 128 + f * 16 + (lane & 15)) * BK + koff]);
#pragma unroll
            for (int f = 0; f < 4; ++f)
                bfr[f] = *(const bf16x8*)(&smB[b][(wn * 64 + f * 16 + (lane & 15)) * BK + koff]);
            __builtin_amdgcn_s_setprio(1);
#pragma unroll
            for (int mf = 0; mf < 8; ++mf)
#pragma unroll
                for (int nf = 0; nf < 4; ++nf)
                    acc[mf][nf] = __builtin_amdgcn_mfma_f32_16x16x32_bf16(
                        af[mf], bfr[nf], acc[mf][nf], 0, 0, 0);
            __builtin_amdgcn_s_setprio(0);
        }
        asm volatile("" ::: "memory");
        __builtin_amdgcn_s_barrier();                // buf b^1 free to restage
    }

    // ---- fused head epilogue ----
    // C/D layout (verified m89/m91): col = lane&15, row = rq*4 + reg.
    float ftb[4]; int cols[4];
#pragma unroll
    for (int nf = 0; nf < 4; ++nf) {
        cols[nf] = tileN + wn * 64 + nf * 16 + (lane & 15);
        ftb[nf]  = ft_b[cols[nf]];
    }
    const int sideoff = (tileM >= B_SZ) ? FT_OUT : 0;   // nstm half of out_w

#pragma unroll
    for (int mf = 0; mf < 8; ++mf) {
#pragma unroll
        for (int r = 0; r < 4; ++r) {
            int mloc  = wm * 128 + mf * 16 + rq * 4 + r;
            int board = (tileM + mloc) & (B_SZ - 1);
            int bkt   = buckets[board];
            const float* ow = out_w + bkt * (2 * FT_OUT) + sideoff;
            float p = 0.0f;
#pragma unroll
            for (int nf = 0; nf < 4; ++nf) {
                float h = acc[mf][nf][r] + ftb[nf];
                h = fminf(fmaxf(h, 0.0f), 1.0f);
                p += h * ow[cols[nf]];
            }
            p += __shfl_xor(p, 1);
            p += __shfl_xor(p, 2);
            p += __shfl_xor(p, 4);
            p += __shfl_xor(p, 8);
            if ((lane & 15) == 0) atomicAdd(logit + board, p);
        }
    }
#undef STAGE
}

// ---------------------------------------------------------------------------
// Kernel D: out[b] = sigmoid(logit[b] + out_b[bucket[b]]).
// ---------------------------------------------------------------------------
__global__ __launch_bounds__(256) void finish(const float* __restrict__ logit,
                                              const int* __restrict__ buckets,
                                              const float* __restrict__ out_b,
                                              float* __restrict__ out) {
    int b = blockIdx.x * 256 + threadIdx.x;
    float l = logit[b] + out_b[buckets[b]];
    out[b] = 1.0f / (1.0f + expf(-l));
}

// ===========================================================================
// Fallback (R2 gather path) if ws_size is too small for the dense A matrix.
// ===========================================================================
__global__ __launch_bounds__(256) void transpose_ftw_bf16(
    const float* __restrict__ ft_w, unsigned short* __restrict__ ftT) {
    __shared__ float tile[32][33];
    const int fo = blockIdx.x * 32, oo = blockIdx.y * 32;
    const int tx = threadIdx.x & 31, ty = threadIdx.x >> 5;
#pragma unroll
    for (int i = 0; i < 4; ++i)
        tile[ty + 8 * i][tx] = ft_w[(oo + ty + 8 * i) * FEAT + fo + tx];
    __syncthreads();
#pragma unroll
    for (int i = 0; i < 4; ++i)
        ftT[(fo + ty + 8 * i) * FT_OUT + oo + tx] = f2b(tile[tx][ty + 8 * i]);
}

__global__ __launch_bounds__(256) void nn_fwd(
    const int* __restrict__ stm_idx, const int* __restrict__ nstm_idx,
    const float* __restrict__ values, const int* __restrict__ buckets,
    const unsigned short* __restrict__ ftT, const float* __restrict__ ft_b,
    const float* __restrict__ out_w, const float* __restrict__ out_b,
    float* __restrict__ out) {
    const int wave = threadIdx.x >> 6, lane = threadIdx.x & 63;
    const int b = __builtin_amdgcn_readfirstlane(blockIdx.x * 4 + wave);
    float acc_s[2][8], acc_n[2][8];
#pragma unroll
    for (int c = 0; c < 2; ++c) {
        const float4* fb = (const float4*)(ft_b + c * 512 + lane * 8);
        float4 b0 = fb[0], b1 = fb[1];
        float t[8] = {b0.x,b0.y,b0.z,b0.w,b1.x,b1.y,b1.z,b1.w};
#pragma unroll
        for (int j = 0; j < 8; ++j) { acc_s[c][j] = t[j]; acc_n[c][j] = t[j]; }
    }
    const int base = b * NNZ;
#pragma unroll 4
    for (int k = 0; k < NNZ; ++k) {
        const int fs = stm_idx[(base + k) * 2 + 1];
        const int fn = nstm_idx[(base + k) * 2 + 1];
        const float v = values[base + k];
        const unsigned short* cs = ftT + fs * FT_OUT;
        const unsigned short* cn = ftT + fn * FT_OUT;
#pragma unroll
        for (int c = 0; c < 2; ++c) {
            short8 ws = *(const short8*)(cs + c * 512 + lane * 8);
            short8 wn2 = *(const short8*)(cn + c * 512 + lane * 8);
#pragma unroll
            for (int j = 0; j < 8; ++j) {
                acc_s[c][j] = fmaf(v, b2f((unsigned short)ws[j]), acc_s[c][j]);
                acc_n[c][j] = fmaf(v, b2f((unsigned short)wn2[j]), acc_n[c][j]);
            }
        }
    }
    const int bkt = __builtin_amdgcn_readfirstlane(buckets[b]);
    const float* ow = out_w + bkt * (2 * FT_OUT);
    float part = 0.0f;
#pragma unroll
    for (int c = 0; c < 2; ++c) {
        const float4* ps = (const float4*)(ow + c * 512 + lane * 8);
        const float4* pn = (const float4*)(ow + FT_OUT + c * 512 + lane * 8);
        float4 s0 = ps[0], s1 = ps[1], n0 = pn[0], n1 = pn[1];
        float sw[8] = {s0.x,s0.y,s0.z,s0.w,s1.x,s1.y,s1.z,s1.w};
        float nw[8] = {n0.x,n0.y,n0.z,n0.w,n1.x,n1.y,n1.z,n1.w};
#pragma unroll
        for (int j = 0; j < 8; ++j) {
            part += fminf(fmaxf(acc_s[c][j], 0.f), 1.f) * sw[j];
            part += fminf(fmaxf(acc_n[c][j], 0.f), 1.f) * nw[j];
        }
    }
#pragma unroll
    for (int off = 32; off >= 1; off >>= 1) part += __shfl_xor(part, off);
    if (lane == 0) out[b] = 1.0f / (1.0f + expf(-(part + out_b[bkt])));
}

// ---------------------------------------------------------------------------
// setup_inputs() order:
//   0 stm_indices  1 nstm_indices  2 values  3 buckets  4 size
//   5 ft_w [1024,768] f32  6 ft_b [1024]  7 out_w [8,2048]  8 out_b [8]
// ---------------------------------------------------------------------------
extern "C" void kernel_launch(void* const* d_in, const int* in_sizes, int n_in,
                              void* d_out, int out_size, void* d_ws, size_t ws_size,
                              hipStream_t stream) {
    const int*   stm_idx  = (const int*)  d_in[0];
    const int*   nstm_idx = (const int*)  d_in[1];
    const float* values   = (const float*)d_in[2];
    const int*   buckets  = (const int*)  d_in[3];
    const float* ft_w     = (const float*)d_in[5];
    const float* ft_b     = (const float*)d_in[6];
    const float* out_w    = (const float*)d_in[7];
    const float* out_b    = (const float*)d_in[8];
    float*       out      = (float*)d_out;

    const size_t szA = (size_t)M_TOT * FEAT * 2;        // 50.3 MB dense boards
    const size_t szW = (size_t)FT_OUT * FEAT * 2;       // 1.5 MB bf16 weights
    const size_t NEED = szA + szW + (size_t)B_SZ * 4;

    if (ws_size >= NEED) {
        unsigned short* A  = (unsigned short*)d_ws;
        unsigned short* W  = (unsigned short*)((char*)d_ws + szA);
        float*          lg = (float*)((char*)d_ws + szA + szW);

        prep<<<PREP_BUILD + PREP_CVT + PREP_ZERO, 256, 0, stream>>>(
            stm_idx, nstm_idx, values, (const float2*)ft_w, (unsigned int*)W,
            A, lg);
        gemm_head<<<(M_TOT / BM) * (FT_OUT / BN), 512, 0, stream>>>(
            A, W, ft_b, out_w, buckets, lg);
        finish<<<B_SZ / 256, 256, 0, stream>>>(lg, buckets, out_b, out);
    } else {
        unsigned short* ftT = (unsigned short*)d_ws;    // 1.5 MB
        transpose_ftw_bf16<<<dim3(FEAT / 32, FT_OUT / 32), 256, 0, stream>>>(ft_w, ftT);
        nn_fwd<<<B_SZ / 4, 256, 0, stream>>>(stm_idx, nstm_idx, values, buckets,
                                             ftT, ft_b, out_w, out_b, out);
    }
}

// Round 9
// 177.097 us; speedup vs baseline: 1.0632x; 1.0632x over previous
//
#include <hip/hip_runtime.h>
#include <hip/hip_bf16.h>
#include <math.h>

// Problem constants (fixed by the reference setup_inputs()).
#define B_SZ    16384
#define NNZ     32
#define FT_OUT  1024
#define FEAT    768
#define BUCKETS 8
#define M_TOT   (2 * B_SZ)        // stm rows then nstm rows

typedef __bf16 bf16x8 __attribute__((ext_vector_type(8)));
typedef float  f32x4  __attribute__((ext_vector_type(4)));
typedef __attribute__((ext_vector_type(8))) short short8;

__device__ __forceinline__ unsigned short f2b(float f) {
    return __bfloat16_as_ushort(__float2bfloat16(f));
}
__device__ __forceinline__ float b2f(unsigned short u) {
    union { unsigned int i; float f; } x; x.i = ((unsigned int)u) << 16; return x.f;
}
__device__ __forceinline__ void gld_lds16(const void* g, void* l) {
    __builtin_amdgcn_global_load_lds(
        (const __attribute__((address_space(1))) unsigned int*)g,
        (__attribute__((address_space(3))) unsigned int*)l, 16, 0, 0);
}

// ---------------------------------------------------------------------------
// Kernel P (fused prep): blocks [0,8192) scatter boards -> dense bf16 A;
// [8192, 8192+1536) cast ft_w fp32->bf16 (WIDE grid this time — R8's 12-block
// strided cvt was a ~20us latency-bound straggler); last 16 zero logit.
// ---------------------------------------------------------------------------
#define PREP_BUILD  8192
#define PREP_CVT    1536          // 1536*256 = FT_OUT*FEAT/2 float2s, 1/thread
#define PREP_ZERO   16

__global__ __launch_bounds__(256) void prep(
    const int*    __restrict__ stm_idx, const int* __restrict__ nstm_idx,
    const float*  __restrict__ values,
    const float2* __restrict__ ftw2,    unsigned int* __restrict__ Wout,
    unsigned short* __restrict__ A,     float* __restrict__ logit) {
    const int bid = blockIdx.x;
    if (bid < PREP_BUILD) {
        __shared__ float rowbuf[4][FEAT];
        const int wave = threadIdx.x >> 6, lane = threadIdx.x & 63;
        const int m = bid * 4 + wave;
        const int board = m & (B_SZ - 1);
        const int* idx = (m >= B_SZ) ? nstm_idx : stm_idx;
        float* rb = rowbuf[wave];
#pragma unroll
        for (int i = 0; i < FEAT / 64; ++i) rb[i * 64 + lane] = 0.0f;
        __syncthreads();
        if (lane < NNZ) {
            int   f = idx[(board * NNZ + lane) * 2 + 1];
            float v = values[board * NNZ + lane];
            atomicAdd(&rb[f], v);   // duplicate (b,f) must SUM (coo.to_dense)
        }
        __syncthreads();
        unsigned int* dst = (unsigned int*)(A + (long)m * FEAT);
#pragma unroll
        for (int i = 0; i < FEAT / 128; ++i) {
            int e = i * 64 + lane;
            unsigned int lo = f2b(rb[2 * e]), hi = f2b(rb[2 * e + 1]);
            dst[e] = lo | (hi << 16);
        }
    } else if (bid < PREP_BUILD + PREP_CVT) {
        int i = (bid - PREP_BUILD) * 256 + threadIdx.x;   // < FT_OUT*FEAT/2
        float2 v = ftw2[i];
        Wout[i] = (unsigned int)f2b(v.x) | ((unsigned int)f2b(v.y) << 16);
    } else {
        int tid = (bid - PREP_BUILD - PREP_CVT) * 256 + threadIdx.x;
        for (int i = tid; i < B_SZ; i += PREP_ZERO * 256) logit[i] = 0.0f;
    }
}

// ---------------------------------------------------------------------------
// Kernel C: 256x256 bf16 MFMA GEMM, 8-phase m201-pattern schedule.
// 4 phases per K-tile (mf-half x ki-half, 16 MFMA each; B-frags carried in
// regs across the 2 mf-phases -> no redundant LDS reads: 8/4/8/4 ds_reads).
// LDS k-half-major [buf][ki][256 rows][32 elems]; staged half = contiguous
// 16KB = 2 gld_lds/thread. Chunk swizzle: physical = j ^ ((row>>1)&3)
// (write-side source pre-swizzle (lane&3)^((lane>>3)&3)) -> wave reads 64
// distinct 16B slots: conflict-free.
// Half-tile conveyor (stage the half freed at the previous phase barrier):
//   PH1: A(t+1)k1   PH2: B(t+2)k0   PH3: A(t+2)k0   PH4: B(t+2)k1
// Counted vmcnt(10) at end-PH2/PH4 only (5 younger half-stages x 2 loads;
// >=5-phase landing margin), never 0 mid-loop. 2 raw barriers/phase,
// sched_barrier(0) pins, setprio around MFMA clusters.
// ---------------------------------------------------------------------------
#define BM 256
#define BN 256
#define BK 64
#define NKT (FEAT / BK)           // 12 K-tiles

__global__ __launch_bounds__(512, 1) void gemm_head(
    const unsigned short* __restrict__ A,   // [M_TOT][FEAT] bf16
    const unsigned short* __restrict__ W,   // [FT_OUT][FEAT] bf16
    const float* __restrict__ ft_b,         // [FT_OUT]
    const float* __restrict__ out_w,        // [BUCKETS][2*FT_OUT]
    const int*   __restrict__ buckets,      // [B_SZ]
    float*       __restrict__ logit)        // [B_SZ], pre-zeroed
{
    __shared__ unsigned short smA[2 * 2 * 256 * 32];   // 64 KB
    __shared__ unsigned short smB[2 * 2 * 256 * 32];   // 64 KB
    const int wv = threadIdx.x >> 6, lane = threadIdx.x & 63;
    const int wm = wv >> 2, wn = wv & 3;             // 2x4 wave grid

    // T1: 512 wgs, xcd = bid&7 owns 64 contiguous ids; n fastest (4 N-tiles).
    const int bid = blockIdx.x;
    const int wg  = (bid & 7) * 64 + (bid >> 3);
    const int tileM = (wg >> 2) * BM;                // 128 M-tiles
    const int tileN = (wg & 3) * BN;                 // 4 N-tiles

    f32x4 acc[8][4] = {};

    const int l15       = lane & 15;
    const int rq        = lane >> 4;                          // k-quarter
    const int sRowOff   = lane >> 2;                          // staging row sub
    const int sColChunk = ((lane & 3) ^ ((lane >> 3) & 3)) * 8; // src pre-swz
    const int rdChunk   = (rq ^ ((lane >> 1) & 3)) * 8;       // read swz

    // stage one k-half (16KB) of one matrix: 2 gld_lds per thread
#define STAGE_HALF(sm, gsrc, gRowBase, TT, KI, DBUF)                          \
    { _Pragma("unroll")                                                       \
      for (int q_ = 0; q_ < 2; ++q_) {                                        \
          const int rr_ = (q_ * 8 + wv) * 16;                                 \
          gld_lds16(gsrc + (long)(gRowBase + rr_ + sRowOff) * FEAT            \
                         + (TT) * BK + (KI) * 32 + sColChunk,                 \
                    sm + (((DBUF) * 2 + (KI)) * 256 + rr_) * 32);             \
      } }

#define LDA(DBUF, KI, FROW) \
    (*(const bf16x8*)(smA + ((((DBUF)*2+(KI))*256 + (FROW) + l15) * 32 + rdChunk)))
#define LDB(DBUF, KI, FROW) \
    (*(const bf16x8*)(smB + ((((DBUF)*2+(KI))*256 + (FROW) + l15) * 32 + rdChunk)))

    // ---- prologue: tiles 0 and 1, all 4 halves each (16 loads/thread) ----
    STAGE_HALF(smB, W, tileN, 0, 0, 0); STAGE_HALF(smA, A, tileM, 0, 0, 0);
    STAGE_HALF(smB, W, tileN, 0, 1, 0); STAGE_HALF(smA, A, tileM, 0, 1, 0);
    STAGE_HALF(smB, W, tileN, 1, 0, 1); STAGE_HALF(smA, A, tileM, 1, 0, 1);
    STAGE_HALF(smB, W, tileN, 1, 1, 1); STAGE_HALF(smA, A, tileM, 1, 1, 1);
    asm volatile("s_waitcnt vmcnt(8)" ::: "memory");   // tile 0 landed
    __builtin_amdgcn_s_barrier();

    bf16x8 af[4], bfr[4];

#define MFMA16(G)                                                             \
    __builtin_amdgcn_s_setprio(1);                                            \
    _Pragma("unroll")                                                         \
    for (int mf = 0; mf < 4; ++mf)                                            \
        _Pragma("unroll")                                                     \
        for (int nf = 0; nf < 4; ++nf)                                        \
            acc[(G)*4+mf][nf] = __builtin_amdgcn_mfma_f32_16x16x32_bf16(      \
                af[mf], bfr[nf], acc[(G)*4+mf][nf], 0, 0, 0);                 \
    __builtin_amdgcn_s_setprio(0);

#define PH_SYNC_IN                                                            \
    __builtin_amdgcn_sched_barrier(0);                                        \
    __builtin_amdgcn_s_barrier();                                             \
    asm volatile("s_waitcnt lgkmcnt(0)" ::: "memory");                        \
    __builtin_amdgcn_sched_barrier(0);

    for (int t = 0; t < NKT; ++t) {
        const int c = t & 1;
        // -------- PH1: B.k0 + A.k0 mf0-3 --------
        if (t >= 1 && t + 1 < NKT) STAGE_HALF(smA, A, tileM, t + 1, 1, (t + 1) & 1);
#pragma unroll
        for (int nf = 0; nf < 4; ++nf) bfr[nf] = LDB(c, 0, wn * 64 + nf * 16);
#pragma unroll
        for (int mf = 0; mf < 4; ++mf) af[mf] = LDA(c, 0, wm * 128 + mf * 16);
        PH_SYNC_IN
        MFMA16(0)
        __builtin_amdgcn_sched_barrier(0);
        __builtin_amdgcn_s_barrier();
        // -------- PH2: A.k0 mf4-7 --------
        if (t + 2 < NKT) STAGE_HALF(smB, W, tileN, t + 2, 0, c);
#pragma unroll
        for (int mf = 0; mf < 4; ++mf) af[mf] = LDA(c, 0, wm * 128 + 64 + mf * 16);
        PH_SYNC_IN
        MFMA16(1)
        asm volatile("s_waitcnt vmcnt(10)" ::: "memory");
        __builtin_amdgcn_sched_barrier(0);
        __builtin_amdgcn_s_barrier();
        // -------- PH3: B.k1 + A.k1 mf0-3 --------
        if (t + 2 < NKT) STAGE_HALF(smA, A, tileM, t + 2, 0, c);
#pragma unroll
        for (int nf = 0; nf < 4; ++nf) bfr[nf] = LDB(c, 1, wn * 64 + nf * 16);
#pragma unroll
        for (int mf = 0; mf < 4; ++mf) af[mf] = LDA(c, 1, wm * 128 + mf * 16);
        PH_SYNC_IN
        MFMA16(0)
        __builtin_amdgcn_sched_barrier(0);
        __builtin_amdgcn_s_barrier();
        // -------- PH4: A.k1 mf4-7 --------
        if (t + 2 < NKT) STAGE_HALF(smB, W, tileN, t + 2, 1, c);
#pragma unroll
        for (int mf = 0; mf < 4; ++mf) af[mf] = LDA(c, 1, wm * 128 + 64 + mf * 16);
        PH_SYNC_IN
        MFMA16(1)
        asm volatile("s_waitcnt vmcnt(10)" ::: "memory");
        __builtin_amdgcn_sched_barrier(0);
        __builtin_amdgcn_s_barrier();
    }

    // ---- fused head epilogue ----
    // C/D layout (verified m89/m91): col = lane&15, row = rq*4 + reg.
    float ftb[4]; int cols[4];
#pragma unroll
    for (int nf = 0; nf < 4; ++nf) {
        cols[nf] = tileN + wn * 64 + nf * 16 + l15;
        ftb[nf]  = ft_b[cols[nf]];
    }
    const int sideoff = (tileM >= B_SZ) ? FT_OUT : 0;   // nstm half of out_w

#pragma unroll
    for (int mf = 0; mf < 8; ++mf) {
#pragma unroll
        for (int r = 0; r < 4; ++r) {
            int mloc  = wm * 128 + mf * 16 + rq * 4 + r;
            int board = (tileM + mloc) & (B_SZ - 1);
            int bkt   = buckets[board];
            const float* ow = out_w + bkt * (2 * FT_OUT) + sideoff;
            float p = 0.0f;
#pragma unroll
            for (int nf = 0; nf < 4; ++nf) {
                float h = acc[mf][nf][r] + ftb[nf];
                h = fminf(fmaxf(h, 0.0f), 1.0f);
                p += h * ow[cols[nf]];
            }
            p += __shfl_xor(p, 1);
            p += __shfl_xor(p, 2);
            p += __shfl_xor(p, 4);
            p += __shfl_xor(p, 8);
            if ((lane & 15) == 0) atomicAdd(logit + board, p);
        }
    }
#undef STAGE_HALF
#undef LDA
#undef LDB
#undef MFMA16
#undef PH_SYNC_IN
}

// ---------------------------------------------------------------------------
// Kernel D: out[b] = sigmoid(logit[b] + out_b[bucket[b]]).
// ---------------------------------------------------------------------------
__global__ __launch_bounds__(256) void finish(const float* __restrict__ logit,
                                              const int* __restrict__ buckets,
                                              const float* __restrict__ out_b,
                                              float* __restrict__ out) {
    int b = blockIdx.x * 256 + threadIdx.x;
    float l = logit[b] + out_b[buckets[b]];
    out[b] = 1.0f / (1.0f + expf(-l));
}

// ===========================================================================
// Fallback (R2 gather path) if ws_size is too small for the dense A matrix.
// ===========================================================================
__global__ __launch_bounds__(256) void transpose_ftw_bf16(
    const float* __restrict__ ft_w, unsigned short* __restrict__ ftT) {
    __shared__ float tile[32][33];
    const int fo = blockIdx.x * 32, oo = blockIdx.y * 32;
    const int tx = threadIdx.x & 31, ty = threadIdx.x >> 5;
#pragma unroll
    for (int i = 0; i < 4; ++i)
        tile[ty + 8 * i][tx] = ft_w[(oo + ty + 8 * i) * FEAT + fo + tx];
    __syncthreads();
#pragma unroll
    for (int i = 0; i < 4; ++i)
        ftT[(fo + ty + 8 * i) * FT_OUT + oo + tx] = f2b(tile[tx][ty + 8 * i]);
}

__global__ __launch_bounds__(256) void nn_fwd(
    const int* __restrict__ stm_idx, const int* __restrict__ nstm_idx,
    const float* __restrict__ values, const int* __restrict__ buckets,
    const unsigned short* __restrict__ ftT, const float* __restrict__ ft_b,
    const float* __restrict__ out_w, const float* __restrict__ out_b,
    float* __restrict__ out) {
    const int wave = threadIdx.x >> 6, lane = threadIdx.x & 63;
    const int b = __builtin_amdgcn_readfirstlane(blockIdx.x * 4 + wave);
    float acc_s[2][8], acc_n[2][8];
#pragma unroll
    for (int c = 0; c < 2; ++c) {
        const float4* fb = (const float4*)(ft_b + c * 512 + lane * 8);
        float4 b0 = fb[0], b1 = fb[1];
        float t[8] = {b0.x,b0.y,b0.z,b0.w,b1.x,b1.y,b1.z,b1.w};
#pragma unroll
        for (int j = 0; j < 8; ++j) { acc_s[c][j] = t[j]; acc_n[c][j] = t[j]; }
    }
    const int base = b * NNZ;
#pragma unroll 4
    for (int k = 0; k < NNZ; ++k) {
        const int fs = stm_idx[(base + k) * 2 + 1];
        const int fn = nstm_idx[(base + k) * 2 + 1];
        const float v = values[base + k];
        const unsigned short* cs = ftT + fs * FT_OUT;
        const unsigned short* cn = ftT + fn * FT_OUT;
#pragma unroll
        for (int c = 0; c < 2; ++c) {
            short8 ws = *(const short8*)(cs + c * 512 + lane * 8);
            short8 wn2 = *(const short8*)(cn + c * 512 + lane * 8);
#pragma unroll
            for (int j = 0; j < 8; ++j) {
                acc_s[c][j] = fmaf(v, b2f((unsigned short)ws[j]), acc_s[c][j]);
                acc_n[c][j] = fmaf(v, b2f((unsigned short)wn2[j]), acc_n[c][j]);
            }
        }
    }
    const int bkt = __builtin_amdgcn_readfirstlane(buckets[b]);
    const float* ow = out_w + bkt * (2 * FT_OUT);
    float part = 0.0f;
#pragma unroll
    for (int c = 0; c < 2; ++c) {
        const float4* ps = (const float4*)(ow + c * 512 + lane * 8);
        const float4* pn = (const float4*)(ow + FT_OUT + c * 512 + lane * 8);
        float4 s0 = ps[0], s1 = ps[1], n0 = pn[0], n1 = pn[1];
        float sw[8] = {s0.x,s0.y,s0.z,s0.w,s1.x,s1.y,s1.z,s1.w};
        float nw[8] = {n0.x,n0.y,n0.z,n0.w,n1.x,n1.y,n1.z,n1.w};
#pragma unroll
        for (int j = 0; j < 8; ++j) {
            part += fminf(fmaxf(acc_s[c][j], 0.f), 1.f) * sw[j];
            part += fminf(fmaxf(acc_n[c][j], 0.f), 1.f) * nw[j];
        }
    }
#pragma unroll
    for (int off = 32; off >= 1; off >>= 1) part += __shfl_xor(part, off);
    if (lane == 0) out[b] = 1.0f / (1.0f + expf(-(part + out_b[bkt])));
}

// ---------------------------------------------------------------------------
// setup_inputs() order:
//   0 stm_indices  1 nstm_indices  2 values  3 buckets  4 size
//   5 ft_w [1024,768] f32  6 ft_b [1024]  7 out_w [8,2048]  8 out_b [8]
// ---------------------------------------------------------------------------
extern "C" void kernel_launch(void* const* d_in, const int* in_sizes, int n_in,
                              void* d_out, int out_size, void* d_ws, size_t ws_size,
                              hipStream_t stream) {
    const int*   stm_idx  = (const int*)  d_in[0];
    const int*   nstm_idx = (const int*)  d_in[1];
    const float* values   = (const float*)d_in[2];
    const int*   buckets  = (const int*)  d_in[3];
    const float* ft_w     = (const float*)d_in[5];
    const float* ft_b     = (const float*)d_in[6];
    const float* out_w    = (const float*)d_in[7];
    const float* out_b    = (const float*)d_in[8];
    float*       out      = (float*)d_out;

    const size_t szA = (size_t)M_TOT * FEAT * 2;        // 50.3 MB dense boards
    const size_t szW = (size_t)FT_OUT * FEAT * 2;       // 1.5 MB bf16 weights
    const size_t NEED = szA + szW + (size_t)B_SZ * 4;

    if (ws_size >= NEED) {
        unsigned short* A  = (unsigned short*)d_ws;
        unsigned short* W  = (unsigned short*)((char*)d_ws + szA);
        float*          lg = (float*)((char*)d_ws + szA + szW);

        prep<<<PREP_BUILD + PREP_CVT + PREP_ZERO, 256, 0, stream>>>(
            stm_idx, nstm_idx, values, (const float2*)ft_w, (unsigned int*)W,
            A, lg);
        gemm_head<<<(M_TOT / BM) * (FT_OUT / BN), 512, 0, stream>>>(
            A, W, ft_b, out_w, buckets, lg);
        finish<<<B_SZ / 256, 256, 0, stream>>>(lg, buckets, out_b, out);
    } else {
        unsigned short* ftT = (unsigned short*)d_ws;    // 1.5 MB
        transpose_ftw_bf16<<<dim3(FEAT / 32, FT_OUT / 32), 256, 0, stream>>>(ft_w, ftT);
        nn_fwd<<<B_SZ / 4, 256, 0, stream>>>(stm_idx, nstm_idx, values, buckets,
                                             ftT, ft_b, out_w, out_b, out);
    }
}